// Round 9
// baseline (173.298 us; speedup 1.0000x reference)
//
#include <hip/hip_runtime.h>
#include <stdint.h>

// ---- JAX PRNG path: 1 = jax_threefry_partitionable (modern default), 0 = legacy split-iota
#define JAX_PARTITIONABLE 1

#define SNUM 10
#define NBATCH 4
#define NCLS 4
#define HH 512
#define WW 512
#define IMG (HH*WW)                   // 262144
#define NPIX (SNUM*NBATCH*IMG)        // 10485760
#define GUMTOT ((uint32_t)NPIX*NCLS)  // 41943040
#define HALFG (GUMTOT/2u)             // 20971520
#define WPI (IMG/32)                  // 8192 32-bit words per 512x512 image
#define QCAP 3584                     // BFS fallback queue entries

#if __has_builtin(__builtin_amdgcn_alignbit)
__device__ __forceinline__ uint32_t rotl32(uint32_t x, int r) {
  return __builtin_amdgcn_alignbit(x, x, (uint32_t)(32 - r));  // v_alignbit_b32 = rotr
}
#else
__device__ __forceinline__ uint32_t rotl32(uint32_t x, int r) {
  return (x << r) | (x >> (32 - r));
}
#endif

// Threefry-2x32, key = (0, 42)  [jax.random.key(42)]
__device__ __forceinline__ void tf2x32(uint32_t x0, uint32_t x1,
                                       uint32_t& o0, uint32_t& o1) {
  const uint32_t k0 = 0u, k1 = 42u;
  const uint32_t k2 = k0 ^ k1 ^ 0x1BD11BDAu;
  x0 += k0; x1 += k1;
#define TFR(r) { x0 += x1; x1 = rotl32(x1, (r)); x1 ^= x0; }
  TFR(13) TFR(15) TFR(26) TFR(6)
  x0 += k1; x1 += k2 + 1u;
  TFR(17) TFR(29) TFR(16) TFR(24)
  x0 += k2; x1 += k0 + 2u;
  TFR(13) TFR(15) TFR(26) TFR(6)
  x0 += k0; x1 += k1 + 3u;
  TFR(17) TFR(29) TFR(16) TFR(24)
  x0 += k1; x1 += k2 + 4u;
  TFR(13) TFR(15) TFR(26) TFR(6)
  x0 += k2; x1 += k0 + 5u;
#undef TFR
  o0 = x0; o1 = x1;
}

// JAX uniform(minval=tiny, maxval=1): f01 in [0,1) has min positive 2^-23,
// so f01 + tiny == f01 for f01 > 0, and == tiny for f01 == 0  ->  fmaxf.
__device__ __forceinline__ float u01(uint32_t bits) {
  const float f = __uint_as_float((bits >> 9) | 0x3f800000u) - 1.0f;
  return fmaxf(f, 1.17549435e-38f);
}

__device__ __forceinline__ uint32_t gum_bits(uint32_t g) {
#if JAX_PARTITIONABLE
  uint32_t y0, y1;
  tf2x32(0u, g, y0, y1);
  return y0 ^ y1;
#else
  uint32_t y0, y1;
  uint32_t j = (g < HALFG) ? g : (g - HALFG);
  tf2x32(j, j + HALFG, y0, y1);
  return (g < HALFG) ? y0 : y1;
#endif
}

// unpack: 64-bit packed 2-bit classes XORed with k-pattern -> mask of fields==k
__device__ __forceinline__ uint32_t unpack32(uint64_t v) {
  uint64_t tt = v | (v >> 1);
  uint64_t u = ~tt & 0x5555555555555555ULL;
  u = (u ^ (u >> 1))  & 0x3333333333333333ULL;
  u = (u ^ (u >> 2))  & 0x0F0F0F0F0F0F0F0FULL;
  u = (u ^ (u >> 4))  & 0x00FF00FF00FF00FFULL;
  u = (u ^ (u >> 8))  & 0x0000FFFF0000FFFFULL;
  u = (u ^ (u >> 16)) & 0x00000000FFFFFFFFULL;
  return (uint32_t)u;
}

// ---------------- Kernel A: categorical sampling (validated R6-R8 arithmetic) ----------------
// argmax_c[gumbel_c + log(p_c+eps)] == argmax over p_c/(-log2 u_c) (ln2 & eps
// provably no-op in f32); cross-multiply compare on raw log2 (l<=0):
// winner condition p_c*l_best < p_best*l_c.
__global__ __launch_bounds__(256) void k_sample(const float* __restrict__ preds,
                                                uint8_t* __restrict__ packed,
                                                float* __restrict__ acc,
                                                uint32_t* __restrict__ misc) {
  const int t = blockIdx.x * 256 + threadIdx.x;   // < 2,621,440
  if (t == 0) { acc[0] = 0.0f; misc[0] = 0u; }    // loss accumulator, filldone
  const int sn = t >> 16;                         // s*4 + n
  const int n  = sn & 3;
  const int pg = t & 65535;
  const int pix = pg << 2;

  float pp[NCLS][4];
#pragma unroll
  for (int c = 0; c < NCLS; ++c) {
    const float4 v = *reinterpret_cast<const float4*>(
        preds + (((int64_t)(n * NCLS + c)) << 18) + pix);
    pp[c][0] = v.x; pp[c][1] = v.y; pp[c][2] = v.z; pp[c][3] = v.w;
  }

  const uint32_t gb = (uint32_t)sn * 1048576u + ((uint32_t)pix << 2);
  uint32_t byte = 0;
#pragma unroll
  for (int j = 0; j < 4; ++j) {
    float bp = pp[0][j];
    float bl = __log2f(u01(gum_bits(gb + (uint32_t)(j * 4))));   // <= 0
    int bc = 0;
#pragma unroll
    for (int c = 1; c < NCLS; ++c) {
      const float lc = __log2f(u01(gum_bits(gb + (uint32_t)(j * 4 + c))));
      if (pp[c][j] * bl < bp * lc) { bp = pp[c][j]; bl = lc; bc = c; }
    }
    byte |= (uint32_t)bc << (2 * j);
  }
  packed[t] = (uint8_t)byte;
}

// ---- BFS fallback helpers (validated R2/R4) ----

__device__ __forceinline__ uint32_t runmask(uint32_t m, uint32_t s) {
  uint32_t out = 0;
  while (s) {
    const int j = __ffs(s) - 1;
    const uint32_t bj = 1u << j;
    const uint32_t up = ((m + bj) ^ m) & m;
    const uint32_t rm = __brev(m);
    const uint32_t rbj = 1u << (31 - j);
    const uint32_t dn = __brev(((rm + rbj) ^ rm) & rm);
    const uint32_t run = up | dn;
    out |= run;
    s &= ~run;
  }
  return out;
}

__device__ __forceinline__ void claimf(uint32_t* fg, uint32_t* qw, uint32_t* qb,
                                       uint32_t* qtail, uint32_t t, uint32_t want) {
  const uint32_t old = atomicAnd(&fg[t], ~want);
  uint32_t nb = old & want;
  if (!nb) return;
  const uint32_t ext = runmask(old, nb) & ~nb;
  if (ext) {
    const uint32_t old2 = atomicAnd(&fg[t], ~ext);
    nb |= old2 & ext;
  }
  const uint32_t slot = atomicAdd(qtail, 1u);
  if (slot < QCAP) { qw[slot] = t; qb[slot] = nb; }
}

__device__ __forceinline__ uint64_t shup64(uint64_t v) {
  const uint32_t lo = __shfl_up((unsigned int)v, 1, 64);
  const uint32_t hi = __shfl_up((unsigned int)(v >> 32), 1, 64);
  return ((uint64_t)hi << 32) | lo;
}
__device__ __forceinline__ uint64_t shdn64(uint64_t v) {
  const uint32_t lo = __shfl_down((unsigned int)v, 1, 64);
  const uint32_t hi = __shfl_down((unsigned int)(v >> 32), 1, 64);
  return ((uint64_t)hi << 32) | lo;
}

// ---------------- Kernel B: one block per prob — argmax + fill + final ----------------
// 120 blocks x 1024 threads. Full fg bitmask in LDS (R2 structure); whole-image
// 5x5-count argmax in-block (R2 code, stride 1024); wave 0 does the R4 windowed
// register fill from LDS; R4 BFS fallback on the already-built LDS fg.
// No inter-block dependencies; merged final via 120 fenced atomics (R8-validated).
__global__ __launch_bounds__(1024) void k_tail(const float* __restrict__ preds,
                                               const uint8_t* __restrict__ packed,
                                               uint32_t* __restrict__ misc,
                                               float* __restrict__ acc,
                                               float* __restrict__ out) {
  __shared__ uint32_t fg[WPI];     // 32 KB
  __shared__ uint32_t qw[QCAP];    // 14 KB (BFS fallback)
  __shared__ uint32_t qb[QCAP];    // 14 KB
  __shared__ uint32_t skey;
  __shared__ uint32_t qtail;
  const int tid = threadIdx.x;     // 0..1023
  const int prob = blockIdx.x;
  const int sn = prob % 40;        // s*4 + n
  const int k  = 1 + prob / 40;    // fg class 1..3
  const int n  = sn & 3;

  if (tid == 0) { skey = 0u; qtail = 0u; }

  // Build full fg bitmask from packed classes
  const uint64_t* p64 = reinterpret_cast<const uint64_t*>(packed);
  const uint64_t pat = (uint64_t)k * 0x5555555555555555ULL;
  for (int wi = tid; wi < WPI; wi += 1024)
    fg[wi] = unpack32(p64[(int64_t)sn * WPI + wi] ^ pat);
  __syncthreads();

  // 5x5 neighbor-count argmax, first-flat-index tie-break (R2 verbatim, stride 1024)
  uint32_t lbest = 0;
  for (int wi = tid; wi < WPI; wi += 1024) {
    const uint32_t cw = fg[wi];
    if (!cw) continue;
    const int row = wi >> 4, col = wi & 15;
    uint64_t rb[5];
#pragma unroll
    for (int d = 0; d < 5; ++d) {
      const int rr = row + d - 2;
      if (rr < 0 || rr >= HH) { rb[d] = 0; continue; }
      const int base = (rr << 4) + col;
      const uint32_t le = (col > 0)  ? fg[base - 1] : 0u;
      const uint32_t cu = fg[base];
      const uint32_t ri = (col < 15) ? fg[base + 1] : 0u;
      rb[d] = ((uint64_t)(ri & 7u) << 34) | ((uint64_t)cu << 2) | (uint64_t)(le >> 30);
    }
    uint32_t bits = cw;
    while (bits) {
      const int j = __ffs(bits) - 1;
      bits &= bits - 1;
      int cnt = 0;
#pragma unroll
      for (int d = 0; d < 5; ++d)
        cnt += __popc((uint32_t)(rb[d] >> j) & 0x1fu);
      const uint32_t key = ((uint32_t)cnt << 18) | (0x3FFFFu - (uint32_t)(wi * 32 + j));
      lbest = lbest > key ? lbest : key;
    }
  }
#pragma unroll
  for (int off = 32; off > 0; off >>= 1) {
    const uint32_t o = (uint32_t)__shfl_down((int)lbest, off, 64);
    lbest = lbest > o ? lbest : o;
  }
  if ((tid & 63) == 0 && lbest) atomicMax(&skey, lbest);
  __syncthreads();
  const uint32_t bkey = skey;

  if (tid >= 64) return;               // single wave from here; no more barriers

  float local = 0.0f;
  if ((bkey >> 18) != 0u) {
    const uint32_t seed = 0x3FFFFu - (bkey & 0x3FFFFu);
    const int sr = (int)(seed >> 9), sc = (int)(seed & 511);
    const float* chan = preds + (((int64_t)n) * NCLS + k) * (int64_t)IMG;

    // ---- windowed register flood fill: 64 rows x 64 cols around the seed (R4) ----
    int r0 = sr - 31; if (r0 < 0) r0 = 0; if (r0 > HH - 64) r0 = HH - 64;
    int cl = (sc >> 5) - (((sc & 31) < 16) ? 1 : 0);
    if (cl < 0) cl = 0; if (cl > 14) cl = 14;
    const int ar = r0 + tid;                  // this lane's absolute row
    const uint64_t fgw = ((uint64_t)fg[(ar << 4) + cl + 1] << 32) | fg[(ar << 4) + cl];
    uint64_t fill = (ar == sr) ? (1ULL << (sc - (cl << 5))) : 0ULL;

    bool conv = false;
    for (int it = 0; it < 2048; ++it) {
      uint64_t up = shup64(fill); if (tid == 0)  up = 0ULL;
      uint64_t dn = shdn64(fill); if (tid == 63) dn = 0ULL;
      const uint64_t sp = fill | up | dn;
      const uint64_t nf = (fgw & (sp | (sp << 1) | (sp >> 1))) | fill;
      const bool ch = (nf != fill);
      fill = nf;
      if (__ballot(ch) == 0ULL) { conv = true; break; }
    }

    bool esc = !conv;
    if (fill) {
      if (tid == 0 && r0 > 0) esc = true;
      if (tid == 63 && r0 + 63 < HH - 1) esc = true;
      if ((fill & 1ULL) && cl > 0) esc = true;
      if ((fill >> 63) && cl < 14) esc = true;
    }

    if (__ballot(esc) == 0ULL) {
      uint64_t bits = fill;
      const float* rowp = chan + (int64_t)ar * WW + (cl << 5);
      while (bits) {
        const int j = __ffsll((unsigned long long)bits) - 1;
        bits &= bits - 1;
        local += logf(rowp[j] + 1e-16f);
      }
    } else {
      // ---- rare fallback: exact word-level BFS on the already-built LDS fg (R4) ----
      claimf(fg, qw, qb, &qtail, seed >> 5, 1u << (seed & 31));
      uint32_t head = 0;
      while (true) {
        uint32_t tail = atomicAdd(&qtail, 0u);
        if (tail > QCAP) tail = QCAP;
        if (head >= tail) break;
        for (uint32_t i = head + (uint32_t)tid; i < tail; i += 64) {
          const uint32_t w = qw[i], got = qb[i];
          const int row = (int)(w >> 4), cb = (int)(w & 15);
          const uint32_t spread = got | (got << 1) | (got >> 1);
          const bool lo = (got & 1u) != 0u, hi = (got >> 31) != 0u;
          if (row > 0) {
            claimf(fg, qw, qb, &qtail, w - 16, spread);
            if (cb > 0 && lo)  claimf(fg, qw, qb, &qtail, w - 17, 0x80000000u);
            if (cb < 15 && hi) claimf(fg, qw, qb, &qtail, w - 15, 1u);
          }
          if (row < HH - 1) {
            claimf(fg, qw, qb, &qtail, w + 16, spread);
            if (cb > 0 && lo)  claimf(fg, qw, qb, &qtail, w + 15, 0x80000000u);
            if (cb < 15 && hi) claimf(fg, qw, qb, &qtail, w + 17, 1u);
          }
          if (cb > 0 && lo)  claimf(fg, qw, qb, &qtail, w - 1, 0x80000000u);
          if (cb < 15 && hi) claimf(fg, qw, qb, &qtail, w + 1, 1u);
        }
        head = tail;
      }
      uint32_t tot = qtail; if (tot > QCAP) tot = QCAP;
      for (uint32_t i = (uint32_t)tid; i < tot; i += 64) {
        const uint32_t w = qw[i];
        uint32_t bits = qb[i];
        const int row = (int)(w >> 4);
        const int colb = (int)(w & 15) << 5;
        const float* rowp = chan + (int64_t)row * WW;
        while (bits) {
          const int j = __ffs(bits) - 1;
          bits &= bits - 1;
          local += logf(rowp[colb + j] + 1e-16f);
        }
      }
    }
  }

  // epilogue: reduce, accumulate; last of the 120 blocks writes out[0] (R8)
#pragma unroll
  for (int off = 32; off > 0; off >>= 1)
    local += __shfl_down(local, off, 64);
  if (tid == 0) {
    if (local != 0.0f) atomicAdd(acc, local);
    __threadfence();
    const uint32_t old = atomicAdd(misc, 1u);
    if (old == 119u) {
      const float s = atomicAdd(acc, 0.0f);      // coherent read of final sum
      out[0] = -s / 10485760.0f;
    }
  }
}

extern "C" void kernel_launch(void* const* d_in, const int* in_sizes, int n_in,
                              void* d_out, int out_size, void* d_ws, size_t ws_size,
                              hipStream_t stream) {
  const float* preds = (const float*)d_in[0];
  float* out = (float*)d_out;
  char* ws = (char*)d_ws;
  // ws layout: acc@0 | misc@64 (filldone) | packed@4096 (2.62 MB)
  float*    acc    = (float*)ws;
  uint32_t* misc   = (uint32_t*)(ws + 64);
  uint8_t*  packed = (uint8_t*)(ws + 4096);

  k_sample<<<10240, 256, 0, stream>>>(preds, packed, acc, misc);
  k_tail<<<120, 1024, 0, stream>>>(preds, packed, misc, acc, out);
}

// Round 10
// 160.149 us; speedup vs baseline: 1.0821x; 1.0821x over previous
//
#include <hip/hip_runtime.h>
#include <stdint.h>

// ---- JAX PRNG path: 1 = jax_threefry_partitionable (modern default), 0 = legacy split-iota
#define JAX_PARTITIONABLE 1

#define SNUM 10
#define NBATCH 4
#define NCLS 4
#define HH 512
#define WW 512
#define IMG (HH*WW)                   // 262144
#define NPIX (SNUM*NBATCH*IMG)        // 10485760
#define GUMTOT ((uint32_t)NPIX*NCLS)  // 41943040
#define HALFG (GUMTOT/2u)             // 20971520
#define WPI (IMG/32)                  // 8192 32-bit words per 512x512 image
#define QCAP 3584                     // BFS fallback queue entries

#if __has_builtin(__builtin_amdgcn_alignbit)
__device__ __forceinline__ uint32_t rotl32(uint32_t x, int r) {
  return __builtin_amdgcn_alignbit(x, x, (uint32_t)(32 - r));  // v_alignbit_b32 = rotr
}
#else
__device__ __forceinline__ uint32_t rotl32(uint32_t x, int r) {
  return (x << r) | (x >> (32 - r));
}
#endif

// Threefry-2x32, key = (0, 42)  [jax.random.key(42)]
__device__ __forceinline__ void tf2x32(uint32_t x0, uint32_t x1,
                                       uint32_t& o0, uint32_t& o1) {
  const uint32_t k0 = 0u, k1 = 42u;
  const uint32_t k2 = k0 ^ k1 ^ 0x1BD11BDAu;
  x0 += k0; x1 += k1;
#define TFR(r) { x0 += x1; x1 = rotl32(x1, (r)); x1 ^= x0; }
  TFR(13) TFR(15) TFR(26) TFR(6)
  x0 += k1; x1 += k2 + 1u;
  TFR(17) TFR(29) TFR(16) TFR(24)
  x0 += k2; x1 += k0 + 2u;
  TFR(13) TFR(15) TFR(26) TFR(6)
  x0 += k0; x1 += k1 + 3u;
  TFR(17) TFR(29) TFR(16) TFR(24)
  x0 += k1; x1 += k2 + 4u;
  TFR(13) TFR(15) TFR(26) TFR(6)
  x0 += k2; x1 += k0 + 5u;
#undef TFR
  o0 = x0; o1 = x1;
}

// JAX uniform(minval=tiny, maxval=1): f01 in [0,1) has min positive 2^-23,
// so f01 + tiny == f01 for f01 > 0, and == tiny for f01 == 0  ->  fmaxf.
__device__ __forceinline__ float u01(uint32_t bits) {
  const float f = __uint_as_float((bits >> 9) | 0x3f800000u) - 1.0f;
  return fmaxf(f, 1.17549435e-38f);
}

__device__ __forceinline__ uint32_t gum_bits(uint32_t g) {
#if JAX_PARTITIONABLE
  uint32_t y0, y1;
  tf2x32(0u, g, y0, y1);
  return y0 ^ y1;
#else
  uint32_t y0, y1;
  uint32_t j = (g < HALFG) ? g : (g - HALFG);
  tf2x32(j, j + HALFG, y0, y1);
  return (g < HALFG) ? y0 : y1;
#endif
}

// unpack: 64-bit packed 2-bit classes XORed with k-pattern -> mask of fields==k
__device__ __forceinline__ uint32_t unpack32(uint64_t v) {
  uint64_t tt = v | (v >> 1);
  uint64_t u = ~tt & 0x5555555555555555ULL;
  u = (u ^ (u >> 1))  & 0x3333333333333333ULL;
  u = (u ^ (u >> 2))  & 0x0F0F0F0F0F0F0F0FULL;
  u = (u ^ (u >> 4))  & 0x00FF00FF00FF00FFULL;
  u = (u ^ (u >> 8))  & 0x0000FFFF0000FFFFULL;
  u = (u ^ (u >> 16)) & 0x00000000FFFFFFFFULL;
  return (uint32_t)u;
}

// ---------------- Kernel A: categorical sampling (validated R6-R8 arithmetic) ----------------
// argmax_c[gumbel_c + log(p_c+eps)] == argmax over p_c/(-log2 u_c) (ln2 & eps
// provably no-op in f32); cross-multiply compare on raw log2 (l<=0):
// winner condition p_c*l_best < p_best*l_c.
__global__ __launch_bounds__(256) void k_sample(const float* __restrict__ preds,
                                                uint8_t* __restrict__ packed,
                                                float* __restrict__ acc,
                                                uint32_t* __restrict__ gkey,
                                                uint32_t* __restrict__ misc) {
  const int t = blockIdx.x * 256 + threadIdx.x;   // < 2,621,440
  if (t == 0) acc[0] = 0.0f;
  if (t < 120) gkey[t] = 0u;
  if (t == 120) misc[0] = 0u;                     // filldone
  const int sn = t >> 16;                         // s*4 + n
  const int n  = sn & 3;
  const int pg = t & 65535;
  const int pix = pg << 2;

  float pp[NCLS][4];
#pragma unroll
  for (int c = 0; c < NCLS; ++c) {
    const float4 v = *reinterpret_cast<const float4*>(
        preds + (((int64_t)(n * NCLS + c)) << 18) + pix);
    pp[c][0] = v.x; pp[c][1] = v.y; pp[c][2] = v.z; pp[c][3] = v.w;
  }

  const uint32_t gb = (uint32_t)sn * 1048576u + ((uint32_t)pix << 2);
  uint32_t byte = 0;
#pragma unroll
  for (int j = 0; j < 4; ++j) {
    float bp = pp[0][j];
    float bl = __log2f(u01(gum_bits(gb + (uint32_t)(j * 4))));   // <= 0
    int bc = 0;
#pragma unroll
    for (int c = 1; c < NCLS; ++c) {
      const float lc = __log2f(u01(gum_bits(gb + (uint32_t)(j * 4 + c))));
      if (pp[c][j] * bl < bp * lc) { bp = pp[c][j]; bl = lc; bc = c; }
    }
    byte |= (uint32_t)bc << (2 * j);
  }
  packed[t] = (uint8_t)byte;
}

// ---------------- Kernel B1: 5x5 neighbor-count argmax (fence-free) ----------------
// 1920 blocks = 120 probs x 16 row-slabs of 32 rows. LDS slab = 36 rows x 16 words.
__global__ __launch_bounds__(256) void k_argmax(const uint8_t* __restrict__ packed,
                                                uint32_t* __restrict__ gkey) {
  __shared__ uint32_t sfg[36 * 16];   // 2304 B
  __shared__ uint32_t skey;
  const int tid = threadIdx.x;
  const int b = blockIdx.x;
  const int prob = b >> 4;
  const int slab = b & 15;
  const int sn = prob % 40;
  const int k  = 1 + prob / 40;
  if (tid == 0) skey = 0u;

  const uint64_t* p64 = reinterpret_cast<const uint64_t*>(packed);
  const uint64_t pat = (uint64_t)k * 0x5555555555555555ULL;
  const int gr0 = slab * 32 - 2;      // first loaded row (may be <0)
  for (int wi = tid; wi < 36 * 16; wi += 256) {
    const int gr = gr0 + (wi >> 4);
    uint32_t m = 0;
    if (gr >= 0 && gr < HH)
      m = unpack32(p64[(int64_t)sn * WPI + (gr << 4) + (wi & 15)] ^ pat);
    sfg[wi] = m;
  }
  __syncthreads();

  uint32_t lbest = 0;
  for (int idx = tid; idx < 512; idx += 256) {    // 2 words per thread
    const int rl = 2 + (idx >> 4);                // local row in LDS
    const int col = idx & 15;
    const uint32_t cw = sfg[(rl << 4) + col];
    if (!cw) continue;
    uint64_t rb[5];
#pragma unroll
    for (int d = 0; d < 5; ++d) {
      const int base = ((rl + d - 2) << 4) + col;
      const uint32_t le = (col > 0)  ? sfg[base - 1] : 0u;
      const uint32_t cu = sfg[base];
      const uint32_t ri = (col < 15) ? sfg[base + 1] : 0u;
      rb[d] = ((uint64_t)(ri & 7u) << 34) | ((uint64_t)cu << 2) | (uint64_t)(le >> 30);
    }
    const int gr = slab * 32 + (idx >> 4);
    uint32_t bits = cw;
    while (bits) {
      const int j = __ffs(bits) - 1;
      bits &= bits - 1;
      int cnt = 0;
#pragma unroll
      for (int d = 0; d < 5; ++d)
        cnt += __popc((uint32_t)(rb[d] >> j) & 0x1fu);
      const uint32_t fidx = (uint32_t)((gr << 9) + (col << 5) + j);
      const uint32_t key = ((uint32_t)cnt << 18) | (0x3FFFFu - fidx);
      lbest = lbest > key ? lbest : key;
    }
  }
#pragma unroll
  for (int off = 32; off > 0; off >>= 1) {
    const uint32_t o = (uint32_t)__shfl_down((int)lbest, off, 64);
    lbest = lbest > o ? lbest : o;
  }
  if ((threadIdx.x & 63) == 0 && lbest) atomicMax(&skey, lbest);
  __syncthreads();
  if (tid == 0 && skey) atomicMax(&gkey[prob], skey);
}

// ---- BFS fallback helpers (validated R2) ----

__device__ __forceinline__ uint32_t runmask(uint32_t m, uint32_t s) {
  uint32_t out = 0;
  while (s) {
    const int j = __ffs(s) - 1;
    const uint32_t bj = 1u << j;
    const uint32_t up = ((m + bj) ^ m) & m;
    const uint32_t rm = __brev(m);
    const uint32_t rbj = 1u << (31 - j);
    const uint32_t dn = __brev(((rm + rbj) ^ rm) & rm);
    const uint32_t run = up | dn;
    out |= run;
    s &= ~run;
  }
  return out;
}

__device__ __forceinline__ void claimf(uint32_t* fg, uint32_t* qw, uint32_t* qb,
                                       uint32_t* qtail, uint32_t t, uint32_t want) {
  const uint32_t old = atomicAnd(&fg[t], ~want);
  uint32_t nb = old & want;
  if (!nb) return;
  const uint32_t ext = runmask(old, nb) & ~nb;
  if (ext) {
    const uint32_t old2 = atomicAnd(&fg[t], ~ext);
    nb |= old2 & ext;
  }
  const uint32_t slot = atomicAdd(qtail, 1u);
  if (slot < QCAP) { qw[slot] = t; qb[slot] = nb; }
}

__device__ __forceinline__ uint64_t shup64(uint64_t v) {
  const uint32_t lo = __shfl_up((unsigned int)v, 1, 64);
  const uint32_t hi = __shfl_up((unsigned int)(v >> 32), 1, 64);
  return ((uint64_t)hi << 32) | lo;
}
__device__ __forceinline__ uint64_t shdn64(uint64_t v) {
  const uint32_t lo = __shfl_down((unsigned int)v, 1, 64);
  const uint32_t hi = __shfl_down((unsigned int)(v >> 32), 1, 64);
  return ((uint64_t)hi << 32) | lo;
}

// ---------------- Kernel B2: windowed flood fill + reward sum + final ----------------
// 120 blocks x 64 threads (one wave). Common path never touches LDS.
// Last-done block writes out[0] (only 120 fences total).
__global__ __launch_bounds__(64) void k_fill(const float* __restrict__ preds,
                                             const uint8_t* __restrict__ packed,
                                             const uint32_t* __restrict__ gkey,
                                             uint32_t* __restrict__ misc,
                                             float* __restrict__ acc,
                                             float* __restrict__ out) {
  __shared__ uint32_t fg[WPI];     // fallback only
  __shared__ uint32_t qw[QCAP];
  __shared__ uint32_t qb[QCAP];
  __shared__ uint32_t qtail;
  const int tid = threadIdx.x;     // 0..63
  const int prob = blockIdx.x;
  const int sn = prob % 40;
  const int k  = 1 + prob / 40;
  const int n  = sn & 3;
  uint32_t* filldone = misc + 0;

  const uint32_t bkey = gkey[prob];
  float local = 0.0f;
  if ((bkey >> 18) != 0u) {
    const uint32_t seed = 0x3FFFFu - (bkey & 0x3FFFFu);
    const int sr = (int)(seed >> 9), sc = (int)(seed & 511);
    const float* chan = preds + (((int64_t)n) * NCLS + k) * (int64_t)IMG;
    const uint64_t* p64 = reinterpret_cast<const uint64_t*>(packed);
    const uint64_t pat = (uint64_t)k * 0x5555555555555555ULL;

    // ---- windowed register flood fill: 64 rows x 64 cols around the seed ----
    int r0 = sr - 31; if (r0 < 0) r0 = 0; if (r0 > HH - 64) r0 = HH - 64;
    int cl = (sc >> 5) - (((sc & 31) < 16) ? 1 : 0);
    if (cl < 0) cl = 0; if (cl > 14) cl = 14;
    const int ar = r0 + tid;                  // this lane's absolute row
    const int64_t pb = (int64_t)sn * WPI + (ar << 4) + cl;
    const uint64_t fgw = ((uint64_t)unpack32(p64[pb + 1] ^ pat) << 32)
                       |            unpack32(p64[pb]     ^ pat);
    uint64_t fill = (ar == sr) ? (1ULL << (sc - (cl << 5))) : 0ULL;

    bool conv = false;
    for (int it = 0; it < 2048; ++it) {
      uint64_t up = shup64(fill); if (tid == 0)  up = 0ULL;
      uint64_t dn = shdn64(fill); if (tid == 63) dn = 0ULL;
      const uint64_t sp = fill | up | dn;
      const uint64_t nf = (fgw & (sp | (sp << 1) | (sp >> 1))) | fill;
      const bool ch = (nf != fill);
      fill = nf;
      if (__ballot(ch) == 0ULL) { conv = true; break; }
    }

    bool esc = !conv;
    if (fill) {
      if (tid == 0 && r0 > 0) esc = true;
      if (tid == 63 && r0 + 63 < HH - 1) esc = true;
      if ((fill & 1ULL) && cl > 0) esc = true;
      if ((fill >> 63) && cl < 14) esc = true;
    }

    if (__ballot(esc) == 0ULL) {
      uint64_t bits = fill;
      const float* rowp = chan + (int64_t)ar * WW + (cl << 5);
      while (bits) {
        const int j = __ffsll((unsigned long long)bits) - 1;
        bits &= bits - 1;
        local += logf(rowp[j] + 1e-16f);
      }
    } else {
      // ---- rare fallback: build full fg in LDS, exact word-level BFS ----
      if (tid == 0) qtail = 0u;
      for (int wi = tid; wi < WPI; wi += 64)
        fg[wi] = unpack32(p64[(int64_t)sn * WPI + wi] ^ pat);
      __syncthreads();
      claimf(fg, qw, qb, &qtail, seed >> 5, 1u << (seed & 31));
      uint32_t head = 0;
      while (true) {
        uint32_t tail = atomicAdd(&qtail, 0u);
        if (tail > QCAP) tail = QCAP;
        if (head >= tail) break;
        for (uint32_t i = head + (uint32_t)tid; i < tail; i += 64) {
          const uint32_t w = qw[i], got = qb[i];
          const int row = (int)(w >> 4), cb = (int)(w & 15);
          const uint32_t spread = got | (got << 1) | (got >> 1);
          const bool lo = (got & 1u) != 0u, hi = (got >> 31) != 0u;
          if (row > 0) {
            claimf(fg, qw, qb, &qtail, w - 16, spread);
            if (cb > 0 && lo)  claimf(fg, qw, qb, &qtail, w - 17, 0x80000000u);
            if (cb < 15 && hi) claimf(fg, qw, qb, &qtail, w - 15, 1u);
          }
          if (row < HH - 1) {
            claimf(fg, qw, qb, &qtail, w + 16, spread);
            if (cb > 0 && lo)  claimf(fg, qw, qb, &qtail, w + 15, 0x80000000u);
            if (cb < 15 && hi) claimf(fg, qw, qb, &qtail, w + 17, 1u);
          }
          if (cb > 0 && lo)  claimf(fg, qw, qb, &qtail, w - 1, 0x80000000u);
          if (cb < 15 && hi) claimf(fg, qw, qb, &qtail, w + 1, 1u);
        }
        head = tail;
      }
      uint32_t tot = qtail; if (tot > QCAP) tot = QCAP;
      for (uint32_t i = (uint32_t)tid; i < tot; i += 64) {
        const uint32_t w = qw[i];
        uint32_t bits = qb[i];
        const int row = (int)(w >> 4);
        const int colb = (int)(w & 15) << 5;
        const float* rowp = chan + (int64_t)row * WW;
        while (bits) {
          const int j = __ffs(bits) - 1;
          bits &= bits - 1;
          local += logf(rowp[colb + j] + 1e-16f);
        }
      }
    }
  }

  // epilogue: reduce, accumulate; last of the 120 blocks writes out[0]
#pragma unroll
  for (int off = 32; off > 0; off >>= 1)
    local += __shfl_down(local, off, 64);
  if (tid == 0) {
    if (local != 0.0f) atomicAdd(acc, local);
    __threadfence();
    const uint32_t old = atomicAdd(filldone, 1u);
    if (old == 119u) {
      const float s = atomicAdd(acc, 0.0f);      // coherent read of final sum
      out[0] = -s / 10485760.0f;
    }
  }
}

extern "C" void kernel_launch(void* const* d_in, const int* in_sizes, int n_in,
                              void* d_out, int out_size, void* d_ws, size_t ws_size,
                              hipStream_t stream) {
  const float* preds = (const float*)d_in[0];
  float* out = (float*)d_out;
  char* ws = (char*)d_ws;
  // ws layout: acc@0 | gkey@64 (120 u32) | misc@1536 | packed@4096 (2.62 MB)
  float*    acc    = (float*)ws;
  uint32_t* gkey   = (uint32_t*)(ws + 64);
  uint32_t* misc   = (uint32_t*)(ws + 1536);
  uint8_t*  packed = (uint8_t*)(ws + 4096);

  k_sample<<<10240, 256, 0, stream>>>(preds, packed, acc, gkey, misc);
  k_argmax<<<1920, 256, 0, stream>>>(packed, gkey);
  k_fill<<<120, 64, 0, stream>>>(preds, packed, gkey, misc, acc, out);
}